// Round 3
// baseline (197.489 us; speedup 1.0000x reference)
//
#include <hip/hip_runtime.h>

typedef __attribute__((ext_vector_type(4))) float f32x4;
typedef __attribute__((ext_vector_type(8))) _Float16 f16x8;
typedef __attribute__((ext_vector_type(2))) __fp16 fp16x2_raw;
typedef __attribute__((ext_vector_type(4))) unsigned int u32x4;
typedef __attribute__((ext_vector_type(2))) unsigned int u32x2;

#define MFMA_F16(a, b, c) __builtin_amdgcn_mfma_f32_16x16x32_f16((a), (b), (c), 0, 0, 0)

__device__ __forceinline__ unsigned int pkrtz(float a, float b) {
  union { fp16x2_raw h; unsigned int u; } v;
  v.h = __builtin_amdgcn_cvt_pkrtz(a, b);
  return v.u;
}

typedef const __attribute__((address_space(1))) unsigned int ga_u32_t;
typedef __attribute__((address_space(3))) unsigned int ls_u32_t;
__device__ __forceinline__ void gload16(const void* g, void* l) {
  __builtin_amdgcn_global_load_lds((ga_u32_t*)g, (ls_u32_t*)l, 16, 0, 0);
}

// ---------- prep: x f32 -> fp16 ----------
__global__ __launch_bounds__(256)
void k_prep_x(const float* __restrict__ in, _Float16* __restrict__ out) {
  int i = (blockIdx.x * 256 + threadIdx.x) * 4;
  f32x4 v = *(const f32x4*)(in + i);
  u32x2 p;
  p.x = pkrtz(v[0], v[1]);
  p.y = pkrtz(v[2], v[3]);
  *(u32x2*)(out + i) = p;
}

// ---------- prep: transpose f32 [512][N] -> fp16 [N][512] ----------
__global__ __launch_bounds__(256)
void k_prep_w(const float* __restrict__ in, _Float16* __restrict__ out, int N) {
  __shared__ float t[64][65];
  const int tid = threadIdx.x;
  const int bn = blockIdx.x * 64, bk = blockIdx.y * 64;
  #pragma unroll
  for (int it = 0; it < 16; ++it) {
    int idx = it * 256 + tid;
    int kk = idx >> 6, nn = idx & 63;
    t[kk][nn] = in[(bk + kk) * N + bn + nn];
  }
  __syncthreads();
  #pragma unroll
  for (int it = 0; it < 16; ++it) {
    int idx = it * 256 + tid;
    int nn = idx >> 6, kk = idx & 63;
    out[(bn + nn) * 512 + bk + kk] = (_Float16)t[kk][nn];
  }
}

// ---------- GEMM1: qkv = x @ w_qkv (fp16), fused RoPE epilogue ----------
__global__ __launch_bounds__(256, 3)
void k_gemm_qkv(const _Float16* __restrict__ xh,
                const _Float16* __restrict__ wT,
                const int* __restrict__ pos_h,
                const int* __restrict__ pos_w,
                _Float16* __restrict__ qh,
                _Float16* __restrict__ kh,
                _Float16* __restrict__ vT) {
  __shared__ char As[8192], Bs[8192];
  const int tid = threadIdx.x;
  const int lane = tid & 63, w = tid >> 6;
  const int lr = lane & 15, g = lane >> 4;
  const int m0 = blockIdx.y * 128;
  const int n0 = blockIdx.x * 128;
  const int wr = w >> 1, wc = w & 1;

  f32x4 acc[4][4];
  #pragma unroll
  for (int i = 0; i < 4; ++i)
    #pragma unroll
    for (int j = 0; j < 4; ++j) acc[i][j] = (f32x4){0.f, 0.f, 0.f, 0.f};

  for (int kt = 0; kt < 16; ++kt) {
    const int k0 = kt * 32;
    __syncthreads();
    #pragma unroll
    for (int it = 0; it < 2; ++it) {
      int idx = it * 256 + tid;
      int r = idx >> 2, ch = idx & 3;
      u32x4 d = *(const u32x4*)(xh + (m0 + r) * 512 + k0 + ch * 8);
      *(u32x4*)(As + (((r << 6) + (ch << 4)) ^ ((r & 7) << 4))) = d;
    }
    #pragma unroll
    for (int it = 0; it < 2; ++it) {
      int idx = it * 256 + tid;
      int r = idx >> 2, ch = idx & 3;
      u32x4 d = *(const u32x4*)(wT + (n0 + r) * 512 + k0 + ch * 8);
      *(u32x4*)(Bs + (((r << 6) + (ch << 4)) ^ ((r & 7) << 4))) = d;
    }
    __syncthreads();

    f16x8 af[4], bf[4];
    #pragma unroll
    for (int mi = 0; mi < 4; ++mi) {
      int r = 64 * wr + 16 * mi + lr;
      af[mi] = *(const f16x8*)(As + (((r << 6) + (g << 4)) ^ ((r & 7) << 4)));
    }
    #pragma unroll
    for (int nj = 0; nj < 4; ++nj) {
      int r = 64 * wc + 16 * nj + lr;
      bf[nj] = *(const f16x8*)(Bs + (((r << 6) + (g << 4)) ^ ((r & 7) << 4)));
    }
    __builtin_amdgcn_s_setprio(1);
    #pragma unroll
    for (int mi = 0; mi < 4; ++mi)
      #pragma unroll
      for (int nj = 0; nj < 4; ++nj)
        acc[mi][nj] = MFMA_F16(af[mi], bf[nj], acc[mi][nj]);
    __builtin_amdgcn_s_setprio(0);
  }

  // epilogue: RoPE (q,k) + permuted-transpose write (v)
  #pragma unroll
  for (int mi = 0; mi < 4; ++mi) {
    const int r0f = m0 + 64 * wr + 16 * mi + 4 * g;
    const int n = r0f >> 11;
    const int t = r0f & 2047;
    #pragma unroll
    for (int nj = 0; nj < 4; ++nj) {
      const int c = n0 + 64 * wc + 16 * nj + lr;
      const int mat = c >> 9;          // 0=q 1=k 2=v
      const int hh = (c >> 6) & 7;
      const int dh = c & 63;
      f32x4 v = acc[mi][nj];
      if (mat == 2) {
        // permute s within 32-block: w32=16c2+4g2+r -> 8g2+4c2+r (here t%4==0)
        int tperm = (t & ~31) + 8 * ((t >> 2) & 3) + 4 * ((t >> 4) & 1);
        u32x2 pk2;
        pk2.x = pkrtz(v[0], v[1]);
        pk2.y = pkrtz(v[2], v[3]);
        *(u32x2*)(vT + (size_t)((n * 8 + hh) * 64 + dh) * 2048 + tperm) = pk2;
      } else {
        const int p = (dh & 31) >> 1;
        const float freq = exp2f((float)p * -0.8304820237218405f);  // theta^(-p/16)
        const int odd = lane & 1;
        const int* posArr = (dh < 32) ? pos_h : pos_w;
        _Float16* dst = mat ? kh : qh;
        const float scale = mat ? 1.0f : 0.125f;  // fold 1/sqrt(64) into q
        #pragma unroll
        for (int i = 0; i < 4; ++i) {
          float val = v[i];
          float oth = __shfl_xor(val, 1);
          float ang = (float)posArr[t + i] * freq;
          float sv, cv;
          __sincosf(ang, &sv, &cv);
          float x1 = odd ? oth : val;
          float x2 = odd ? val : oth;
          float res = odd ? (x1 * sv + x2 * cv) : (x1 * cv - x2 * sv);
          dst[(size_t)((n * 8 + hh) * 2048 + t + i) * 64 + dh] = (_Float16)(res * scale);
        }
      }
    }
  }
}

// ---------- flash attention, swapped-QK layout ----------
// grid 512 (1D, XCD-aware: nh = (bid&7)+8*(bid>>7), qt = (bid>>3)&15)
__global__ __launch_bounds__(256, 3)
void k_attn(const _Float16* __restrict__ qh,
            const _Float16* __restrict__ kh,
            const _Float16* __restrict__ vp,
            _Float16* __restrict__ o_flat) {
  __shared__ char Ks[16384];   // [128 s][64 dh] f16, swz ^((s&7)<<4) (content staged pre-swizzled)
  __shared__ char Vs[16384];   // [64 dh][128 s-perm] f16, swz ^((dh&7)<<4)
  const int tid = threadIdx.x, lane = tid & 63, w = tid >> 6;
  const int lr = lane & 15, g = lane >> 4;
  const int bid = blockIdx.x;
  const int qt = (bid >> 3) & 15;
  const int nh = (bid & 7) + 8 * (bid >> 7);

  // Q fragments (B-operand: col=q=lr, k=dh)
  f16x8 qf[2][2];
  const _Float16* qbase = qh + ((size_t)nh * 2048 + qt * 128 + w * 32) * 64;
  #pragma unroll
  for (int mi = 0; mi < 2; ++mi)
    #pragma unroll
    for (int kg = 0; kg < 2; ++kg)
      qf[mi][kg] = *(const f16x8*)(qbase + (16 * mi + lr) * 64 + kg * 32 + g * 8);

  f32x4 oacc[2][4];
  float m_run[2], l_run[2];
  #pragma unroll
  for (int mi = 0; mi < 2; ++mi) {
    #pragma unroll
    for (int nf = 0; nf < 4; ++nf) oacc[mi][nf] = (f32x4){0.f, 0.f, 0.f, 0.f};
    m_run[mi] = -1.0e30f; l_run[mi] = 0.f;
  }

  const _Float16* kb = kh + (size_t)nh * 2048 * 64;
  const _Float16* vb = vp + (size_t)nh * 64 * 2048;

  for (int kt = 0; kt < 16; ++kt) {
    __syncthreads();
    // stage K: linear LDS dest, source-chunk XOR-permuted (rule 21)
    #pragma unroll
    for (int c = 0; c < 4; ++c) {
      int seg = w * 4 + c;
      int r = seg * 8 + (lane >> 3);
      int ch = lane & 7;
      gload16(kb + (size_t)(kt * 128 + r) * 64 + ((ch ^ (r & 7)) << 3), Ks + seg * 1024);
    }
    // stage V^T(perm)
    #pragma unroll
    for (int c = 0; c < 4; ++c) {
      int seg = w * 4 + c;
      int dh = seg * 4 + (lane >> 4);
      int ch = lane & 15;
      gload16(vb + (size_t)dh * 2048 + kt * 128 + ((ch ^ (dh & 7)) << 3), Vs + seg * 1024);
    }
    __syncthreads();

    // S^T = K Q^T : D col=q=lr, row=s-local=4g+reg
    f32x4 sacc[2][8];
    #pragma unroll
    for (int mi = 0; mi < 2; ++mi)
      #pragma unroll
      for (int sj = 0; sj < 8; ++sj) sacc[mi][sj] = (f32x4){0.f, 0.f, 0.f, 0.f};
    __builtin_amdgcn_s_setprio(1);
    #pragma unroll
    for (int sj = 0; sj < 8; ++sj) {
      int s = sj * 16 + lr;
      int rb = s << 7, sw = (s & 7) << 4;
      #pragma unroll
      for (int kg = 0; kg < 2; ++kg) {
        f16x8 kf = *(const f16x8*)(Ks + ((rb + (kg << 6) + (g << 4)) ^ sw));
        sacc[0][sj] = MFMA_F16(kf, qf[0][kg], sacc[0][sj]);
        sacc[1][sj] = MFMA_F16(kf, qf[1][kg], sacc[1][sj]);
      }
    }
    __builtin_amdgcn_s_setprio(0);

    // in-register online softmax: each lane owns one q-row per mi (32 s-vals local)
    unsigned int pk[2][16];
    #pragma unroll
    for (int mi = 0; mi < 2; ++mi) {
      float mx = sacc[mi][0][0];
      #pragma unroll
      for (int sj = 0; sj < 8; ++sj)
        #pragma unroll
        for (int r = 0; r < 4; ++r) mx = fmaxf(mx, sacc[mi][sj][r]);
      mx = fmaxf(mx, __shfl_xor(mx, 16));
      mx = fmaxf(mx, __shfl_xor(mx, 32));
      float mnew = fmaxf(m_run[mi], mx);
      float corr = __expf(m_run[mi] - mnew);
      m_run[mi] = mnew;
      float rs = 0.f;
      #pragma unroll
      for (int sj = 0; sj < 8; ++sj) {
        f32x4 p4 = sacc[mi][sj];
        p4[0] = __expf(p4[0] - mnew);
        p4[1] = __expf(p4[1] - mnew);
        p4[2] = __expf(p4[2] - mnew);
        p4[3] = __expf(p4[3] - mnew);
        rs += (p4[0] + p4[1]) + (p4[2] + p4[3]);
        pk[mi][2 * sj]     = pkrtz(p4[0], p4[1]);
        pk[mi][2 * sj + 1] = pkrtz(p4[2], p4[3]);
      }
      rs += __shfl_xor(rs, 16);
      rs += __shfl_xor(rs, 32);
      l_run[mi] = l_run[mi] * corr + rs;
      #pragma unroll
      for (int nf = 0; nf < 4; ++nf) oacc[mi][nf] *= corr;
    }

    // O^T += V^T P^T : A = V-frag (perm s), B = packed P (zero cross-lane moves)
    __builtin_amdgcn_s_setprio(1);
    #pragma unroll
    for (int t = 0; t < 4; ++t) {
      f16x8 vf[4];
      #pragma unroll
      for (int nf = 0; nf < 4; ++nf) {
        int dh = 16 * nf + lr;
        vf[nf] = *(const f16x8*)(Vs + (((dh << 8) + (t << 6) + (g << 4)) ^ ((dh & 7) << 4)));
      }
      #pragma unroll
      for (int mi = 0; mi < 2; ++mi) {
        union { unsigned int u[4]; f16x8 h; } pb;
        pb.u[0] = pk[mi][4 * t];
        pb.u[1] = pk[mi][4 * t + 1];
        pb.u[2] = pk[mi][4 * t + 2];
        pb.u[3] = pk[mi][4 * t + 3];
        #pragma unroll
        for (int nf = 0; nf < 4; ++nf)
          oacc[mi][nf] = MFMA_F16(vf[nf], pb.h, oacc[mi][nf]);
      }
    }
    __builtin_amdgcn_s_setprio(0);
  }

  // epilogue: normalize, write fp16 o [8192][512]
  const int n = nh >> 3, h = nh & 7;
  #pragma unroll
  for (int mi = 0; mi < 2; ++mi) {
    float inv = 1.0f / l_run[mi];
    int row = qt * 128 + w * 32 + 16 * mi + lr;
    _Float16* orow = o_flat + ((size_t)(n * 2048 + row)) * 512 + h * 64;
    #pragma unroll
    for (int nf = 0; nf < 4; ++nf) {
      u32x2 pk2;
      pk2.x = pkrtz(oacc[mi][nf][0] * inv, oacc[mi][nf][1] * inv);
      pk2.y = pkrtz(oacc[mi][nf][2] * inv, oacc[mi][nf][3] * inv);
      *(u32x2*)(orow + 16 * nf + 4 * g) = pk2;
    }
  }
}

// ---------- GEMM3: out = o @ w_proj + b (fp16 -> f32) ----------
__global__ __launch_bounds__(256, 3)
void k_gemm_proj(const _Float16* __restrict__ o_flat,
                 const _Float16* __restrict__ wpT,
                 const float* __restrict__ bias,
                 float* __restrict__ out) {
  __shared__ char As[8192], Bs[8192];
  const int tid = threadIdx.x;
  const int lane = tid & 63, w = tid >> 6;
  const int lr = lane & 15, g = lane >> 4;
  const int m0 = blockIdx.y * 128;
  const int n0 = blockIdx.x * 128;
  const int wr = w >> 1, wc = w & 1;

  f32x4 acc[4][4];
  #pragma unroll
  for (int i = 0; i < 4; ++i)
    #pragma unroll
    for (int j = 0; j < 4; ++j) acc[i][j] = (f32x4){0.f, 0.f, 0.f, 0.f};

  for (int kt = 0; kt < 16; ++kt) {
    const int k0 = kt * 32;
    __syncthreads();
    #pragma unroll
    for (int it = 0; it < 2; ++it) {
      int idx = it * 256 + tid;
      int r = idx >> 2, ch = idx & 3;
      u32x4 d = *(const u32x4*)(o_flat + (m0 + r) * 512 + k0 + ch * 8);
      *(u32x4*)(As + (((r << 6) + (ch << 4)) ^ ((r & 7) << 4))) = d;
    }
    #pragma unroll
    for (int it = 0; it < 2; ++it) {
      int idx = it * 256 + tid;
      int r = idx >> 2, ch = idx & 3;
      u32x4 d = *(const u32x4*)(wpT + (n0 + r) * 512 + k0 + ch * 8);
      *(u32x4*)(Bs + (((r << 6) + (ch << 4)) ^ ((r & 7) << 4))) = d;
    }
    __syncthreads();

    f16x8 af[4], bf[4];
    #pragma unroll
    for (int mi = 0; mi < 4; ++mi) {
      int r = 64 * wr + 16 * mi + lr;
      af[mi] = *(const f16x8*)(As + (((r << 6) + (g << 4)) ^ ((r & 7) << 4)));
    }
    #pragma unroll
    for (int nj = 0; nj < 4; ++nj) {
      int r = 64 * wc + 16 * nj + lr;
      bf[nj] = *(const f16x8*)(Bs + (((r << 6) + (g << 4)) ^ ((r & 7) << 4)));
    }
    __builtin_amdgcn_s_setprio(1);
    #pragma unroll
    for (int mi = 0; mi < 4; ++mi)
      #pragma unroll
      for (int nj = 0; nj < 4; ++nj)
        acc[mi][nj] = MFMA_F16(af[mi], bf[nj], acc[mi][nj]);
    __builtin_amdgcn_s_setprio(0);
  }

  #pragma unroll
  for (int mi = 0; mi < 4; ++mi) {
    int r0f = m0 + 64 * wr + 16 * mi + 4 * g;
    #pragma unroll
    for (int nj = 0; nj < 4; ++nj) {
      int c = n0 + 64 * wc + 16 * nj + lr;
      float b = bias[c];
      #pragma unroll
      for (int i = 0; i < 4; ++i)
        out[(size_t)(r0f + i) * 512 + c] = acc[mi][nj][i] + b;
    }
  }
}

extern "C" void kernel_launch(void* const* d_in, const int* in_sizes, int n_in,
                              void* d_out, int out_size, void* d_ws, size_t ws_size,
                              hipStream_t stream) {
  const float* x      = (const float*)d_in[0];
  const int*   pos_h  = (const int*)d_in[1];
  const int*   pos_w  = (const int*)d_in[2];
  const float* w_qkv  = (const float*)d_in[3];
  const float* w_proj = (const float*)d_in[4];
  const float* b_proj = (const float*)d_in[5];
  float* out = (float*)d_out;

  char* ws = (char*)d_ws;
  size_t off = 0;
  auto alloc = [&](size_t bytes) {
    char* p = ws + off;
    off += (bytes + 1023) & ~(size_t)1023;
    return p;
  };
  _Float16* xh     = (_Float16*)alloc((size_t)8192 * 512 * 2);
  _Float16* qh     = (_Float16*)alloc((size_t)32 * 2048 * 64 * 2);
  _Float16* kh     = (_Float16*)alloc((size_t)32 * 2048 * 64 * 2);
  _Float16* vT     = (_Float16*)alloc((size_t)32 * 2048 * 64 * 2);
  _Float16* o_flat = (_Float16*)alloc((size_t)8192 * 512 * 2);
  _Float16* wqT    = (_Float16*)alloc((size_t)1536 * 512 * 2);
  _Float16* wpT    = (_Float16*)alloc((size_t)512 * 512 * 2);

  hipLaunchKernelGGL(k_prep_x, dim3(4096), dim3(256), 0, stream, x, xh);
  hipLaunchKernelGGL(k_prep_w, dim3(24, 8), dim3(256), 0, stream, w_qkv, wqT, 1536);
  hipLaunchKernelGGL(k_prep_w, dim3(8, 8), dim3(256), 0, stream, w_proj, wpT, 512);
  hipLaunchKernelGGL(k_gemm_qkv, dim3(12, 64), dim3(256), 0, stream,
                     xh, wqT, pos_h, pos_w, qh, kh, vT);
  hipLaunchKernelGGL(k_attn, dim3(512), dim3(256), 0, stream, qh, kh, vT, o_flat);
  hipLaunchKernelGGL(k_gemm_proj, dim3(4, 64), dim3(256), 0, stream, o_flat, wpT, b_proj, out);
}

// Round 4
// 115.336 us; speedup vs baseline: 1.7123x; 1.7123x over previous
//
#include <hip/hip_runtime.h>

typedef __attribute__((ext_vector_type(4))) float f32x4;
typedef __attribute__((ext_vector_type(8))) _Float16 f16x8;
typedef __attribute__((ext_vector_type(2))) __fp16 fp16x2_raw;
typedef __attribute__((ext_vector_type(4))) unsigned int u32x4;
typedef __attribute__((ext_vector_type(2))) unsigned int u32x2;

#define MFMA_F16(a, b, c) __builtin_amdgcn_mfma_f32_16x16x32_f16((a), (b), (c), 0, 0, 0)

__device__ __forceinline__ unsigned int pkrtz(float a, float b) {
  union { fp16x2_raw h; unsigned int u; } v;
  v.h = __builtin_amdgcn_cvt_pkrtz(a, b);
  return v.u;
}

typedef const __attribute__((address_space(1))) unsigned int ga_u32_t;
typedef __attribute__((address_space(3))) unsigned int ls_u32_t;
__device__ __forceinline__ void gload16(const void* g, void* l) {
  __builtin_amdgcn_global_load_lds((ga_u32_t*)g, (ls_u32_t*)l, 16, 0, 0);
}

// ---------- prep: x f32 -> fp16 ----------
__global__ __launch_bounds__(256)
void k_prep_x(const float* __restrict__ in, _Float16* __restrict__ out) {
  int i = (blockIdx.x * 256 + threadIdx.x) * 4;
  f32x4 v = *(const f32x4*)(in + i);
  u32x2 p;
  p.x = pkrtz(v[0], v[1]);
  p.y = pkrtz(v[2], v[3]);
  *(u32x2*)(out + i) = p;
}

// ---------- prep: transpose f32 [512][N] -> fp16 [N][512] ----------
__global__ __launch_bounds__(256)
void k_prep_w(const float* __restrict__ in, _Float16* __restrict__ out, int N) {
  __shared__ float t[64][65];
  const int tid = threadIdx.x;
  const int bn = blockIdx.x * 64, bk = blockIdx.y * 64;
  #pragma unroll
  for (int it = 0; it < 16; ++it) {
    int idx = it * 256 + tid;
    int kk = idx >> 6, nn = idx & 63;
    t[kk][nn] = in[(bk + kk) * N + bn + nn];
  }
  __syncthreads();
  #pragma unroll
  for (int it = 0; it < 16; ++it) {
    int idx = it * 256 + tid;
    int nn = idx >> 6, kk = idx & 63;
    out[(bn + nn) * 512 + bk + kk] = (_Float16)t[kk][nn];
  }
}

// ---------- GEMM1: qkv = x @ w_qkv (fp16), fused RoPE epilogue ----------
__global__ __launch_bounds__(256, 3)
void k_gemm_qkv(const _Float16* __restrict__ xh,
                const _Float16* __restrict__ wT,
                const int* __restrict__ pos_h,
                const int* __restrict__ pos_w,
                _Float16* __restrict__ qh,
                _Float16* __restrict__ kh,
                _Float16* __restrict__ vT) {
  __shared__ char As[8192], Bs[8192];
  const int tid = threadIdx.x;
  const int lane = tid & 63, w = tid >> 6;
  const int lr = lane & 15, g = lane >> 4;
  const int m0 = blockIdx.y * 128;
  const int n0 = blockIdx.x * 128;
  const int wr = w >> 1, wc = w & 1;

  f32x4 acc[4][4];
  #pragma unroll
  for (int i = 0; i < 4; ++i)
    #pragma unroll
    for (int j = 0; j < 4; ++j) acc[i][j] = (f32x4){0.f, 0.f, 0.f, 0.f};

  for (int kt = 0; kt < 16; ++kt) {
    const int k0 = kt * 32;
    __syncthreads();
    #pragma unroll
    for (int it = 0; it < 2; ++it) {
      int idx = it * 256 + tid;
      int r = idx >> 2, ch = idx & 3;
      u32x4 d = *(const u32x4*)(xh + (m0 + r) * 512 + k0 + ch * 8);
      *(u32x4*)(As + (((r << 6) + (ch << 4)) ^ ((r & 7) << 4))) = d;
    }
    #pragma unroll
    for (int it = 0; it < 2; ++it) {
      int idx = it * 256 + tid;
      int r = idx >> 2, ch = idx & 3;
      u32x4 d = *(const u32x4*)(wT + (n0 + r) * 512 + k0 + ch * 8);
      *(u32x4*)(Bs + (((r << 6) + (ch << 4)) ^ ((r & 7) << 4))) = d;
    }
    __syncthreads();

    f16x8 af[4], bf[4];
    #pragma unroll
    for (int mi = 0; mi < 4; ++mi) {
      int r = 64 * wr + 16 * mi + lr;
      af[mi] = *(const f16x8*)(As + (((r << 6) + (g << 4)) ^ ((r & 7) << 4)));
    }
    #pragma unroll
    for (int nj = 0; nj < 4; ++nj) {
      int r = 64 * wc + 16 * nj + lr;
      bf[nj] = *(const f16x8*)(Bs + (((r << 6) + (g << 4)) ^ ((r & 7) << 4)));
    }
    __builtin_amdgcn_s_setprio(1);
    #pragma unroll
    for (int mi = 0; mi < 4; ++mi)
      #pragma unroll
      for (int nj = 0; nj < 4; ++nj)
        acc[mi][nj] = MFMA_F16(af[mi], bf[nj], acc[mi][nj]);
    __builtin_amdgcn_s_setprio(0);
  }

  // epilogue: RoPE (q,k) + permuted-transpose write (v)
  #pragma unroll
  for (int mi = 0; mi < 4; ++mi) {
    const int r0f = m0 + 64 * wr + 16 * mi + 4 * g;
    const int n = r0f >> 11;
    const int t = r0f & 2047;
    #pragma unroll
    for (int nj = 0; nj < 4; ++nj) {
      const int c = n0 + 64 * wc + 16 * nj + lr;
      const int mat = c >> 9;          // 0=q 1=k 2=v
      const int hh = (c >> 6) & 7;
      const int dh = c & 63;
      f32x4 v = acc[mi][nj];
      if (mat == 2) {
        // permute s within 32-block: s=16a+4b+c -> kpos=8b+4a+c (here t%4==0)
        int tperm = (t & ~31) + 8 * ((t >> 2) & 3) + 4 * ((t >> 4) & 1);
        u32x2 pk2;
        pk2.x = pkrtz(v[0], v[1]);
        pk2.y = pkrtz(v[2], v[3]);
        *(u32x2*)(vT + (size_t)((n * 8 + hh) * 64 + dh) * 2048 + tperm) = pk2;
      } else {
        const int p = (dh & 31) >> 1;
        const float freq = exp2f((float)p * -0.8304820237218405f);  // theta^(-p/16)
        const int odd = lane & 1;
        const int* posArr = (dh < 32) ? pos_h : pos_w;
        _Float16* dst = mat ? kh : qh;
        const float scale = mat ? 1.0f : 0.125f;  // fold 1/sqrt(64) into q
        #pragma unroll
        for (int i = 0; i < 4; ++i) {
          float val = v[i];
          float oth = __shfl_xor(val, 1);
          float ang = (float)posArr[t + i] * freq;
          float sv, cv;
          __sincosf(ang, &sv, &cv);
          float x1 = odd ? oth : val;
          float x2 = odd ? val : oth;
          float res = odd ? (x1 * sv + x2 * cv) : (x1 * cv - x2 * sv);
          dst[(size_t)((n * 8 + hh) * 2048 + t + i) * 64 + dh] = (_Float16)(res * scale);
        }
      }
    }
  }
}

// ---------- flash attention, swapped-QK, KT=64, dbuf + counted vmcnt ----------
// grid 512 (1D, XCD-aware: nh = (bid&7)+8*(bid>>7), qt = (bid>>3)&15)
__global__ __launch_bounds__(256, 3)
void k_attn(const _Float16* __restrict__ qh,
            const _Float16* __restrict__ kh,
            const _Float16* __restrict__ vp,
            _Float16* __restrict__ o_flat) {
  __shared__ char Ks[2][8192];   // [64 s][64 dh] f16, content pre-swizzled ^((s&7)<<4)
  __shared__ char Vs[2][8192];   // [64 dh][64 s-perm] f16, pre-swizzled ^((dh&7)<<4)
  const int tid = threadIdx.x, lane = tid & 63, w = tid >> 6;
  const int lr = lane & 15, g = lane >> 4;
  const int bid = blockIdx.x;
  const int qt = (bid >> 3) & 15;
  const int nh = (bid & 7) + 8 * (bid >> 7);

  // Q fragments (B-operand: col=q=lr, k=dh)
  f16x8 qf[2][2];
  const _Float16* qbase = qh + ((size_t)nh * 2048 + qt * 128 + w * 32) * 64;
  #pragma unroll
  for (int mi = 0; mi < 2; ++mi)
    #pragma unroll
    for (int kg = 0; kg < 2; ++kg)
      qf[mi][kg] = *(const f16x8*)(qbase + (16 * mi + lr) * 64 + kg * 32 + g * 8);

  f32x4 oacc[2][4];
  float m_run[2], l_run[2];
  #pragma unroll
  for (int mi = 0; mi < 2; ++mi) {
    #pragma unroll
    for (int nf = 0; nf < 4; ++nf) oacc[mi][nf] = (f32x4){0.f, 0.f, 0.f, 0.f};
    m_run[mi] = -1.0e30f; l_run[mi] = 0.f;
  }

  const _Float16* kb = kh + (size_t)nh * 2048 * 64;
  const _Float16* vb = vp + (size_t)nh * 64 * 2048;

  const int rr = lane >> 3, cc = lane & 7;  // staging row-in-seg / chunk
  auto stage = [&](int b, int kt) {
    #pragma unroll
    for (int c = 0; c < 2; ++c) {
      int seg = w * 2 + c;
      int r = seg * 8 + rr;
      gload16(kb + (size_t)(kt * 64 + r) * 64 + ((cc ^ (r & 7)) << 3),
              Ks[b] + seg * 1024);
      gload16(vb + (size_t)r * 2048 + kt * 64 + ((cc ^ (r & 7)) << 3),
              Vs[b] + seg * 1024);
    }
  };

  stage(0, 0);  // prologue: 4 loads in flight

  for (int kt = 0; kt < 32; ++kt) {
    const int cur = kt & 1;
    asm volatile("" ::: "memory");
    __builtin_amdgcn_s_barrier();          // A: all done reading buf cur^1
    if (kt + 1 < 32) {
      stage(cur ^ 1, kt + 1);              // issue next tile (4 loads)
      asm volatile("s_waitcnt vmcnt(4)" ::: "memory");  // current tile arrived
    } else {
      asm volatile("s_waitcnt vmcnt(0)" ::: "memory");
    }
    __builtin_amdgcn_s_barrier();          // B: current tile visible to all
    asm volatile("" ::: "memory");

    const char* Kb = Ks[cur];
    const char* Vb = Vs[cur];

    // S^T = K Q^T : D col=q=lr, row=s-local=16sj+4g+reg
    f32x4 sacc[2][4];
    #pragma unroll
    for (int mi = 0; mi < 2; ++mi)
      #pragma unroll
      for (int sj = 0; sj < 4; ++sj) sacc[mi][sj] = (f32x4){0.f, 0.f, 0.f, 0.f};
    __builtin_amdgcn_s_setprio(1);
    #pragma unroll
    for (int sj = 0; sj < 4; ++sj) {
      int s = sj * 16 + lr;
      int rb = s << 7, sw = (s & 7) << 4;
      #pragma unroll
      for (int kg = 0; kg < 2; ++kg) {
        f16x8 kf = *(const f16x8*)(Kb + ((rb + (kg << 6) + (g << 4)) ^ sw));
        sacc[0][sj] = MFMA_F16(kf, qf[0][kg], sacc[0][sj]);
        sacc[1][sj] = MFMA_F16(kf, qf[1][kg], sacc[1][sj]);
      }
    }
    __builtin_amdgcn_s_setprio(0);

    // in-register online softmax; defer-max (THR=8) skips the rescale pass
    #pragma unroll
    for (int mi = 0; mi < 2; ++mi) {
      float mx = sacc[mi][0][0];
      #pragma unroll
      for (int sj = 0; sj < 4; ++sj)
        #pragma unroll
        for (int r = 0; r < 4; ++r) mx = fmaxf(mx, sacc[mi][sj][r]);
      mx = fmaxf(mx, __shfl_xor(mx, 16));
      mx = fmaxf(mx, __shfl_xor(mx, 32));
      if (!__all(mx - m_run[mi] <= 8.0f)) {
        float mnew = fmaxf(m_run[mi], mx);
        float corr = __expf(m_run[mi] - mnew);
        m_run[mi] = mnew;
        l_run[mi] *= corr;
        #pragma unroll
        for (int nf = 0; nf < 4; ++nf) oacc[mi][nf] *= corr;
      }
      float rs = 0.f;
      #pragma unroll
      for (int sj = 0; sj < 4; ++sj)
        #pragma unroll
        for (int r = 0; r < 4; ++r) {
          float e = __expf(sacc[mi][sj][r] - m_run[mi]);
          sacc[mi][sj][r] = e;
          rs += e;
        }
      rs += __shfl_xor(rs, 16);
      rs += __shfl_xor(rs, 32);
      l_run[mi] += rs;
    }

    // O^T += V^T P^T : A = V-frag (perm s), B = packed P straight from regs
    __builtin_amdgcn_s_setprio(1);
    #pragma unroll
    for (int t = 0; t < 2; ++t) {
      f16x8 vf[4];
      #pragma unroll
      for (int nf = 0; nf < 4; ++nf) {
        int dh = 16 * nf + lr;
        vf[nf] = *(const f16x8*)(Vb + (((dh << 7) + (t << 6) + (g << 4)) ^ ((dh & 7) << 4)));
      }
      #pragma unroll
      for (int mi = 0; mi < 2; ++mi) {
        union { unsigned int u[4]; f16x8 h; } pb;
        pb.u[0] = pkrtz(sacc[mi][2 * t][0], sacc[mi][2 * t][1]);
        pb.u[1] = pkrtz(sacc[mi][2 * t][2], sacc[mi][2 * t][3]);
        pb.u[2] = pkrtz(sacc[mi][2 * t + 1][0], sacc[mi][2 * t + 1][1]);
        pb.u[3] = pkrtz(sacc[mi][2 * t + 1][2], sacc[mi][2 * t + 1][3]);
        #pragma unroll
        for (int nf = 0; nf < 4; ++nf)
          oacc[mi][nf] = MFMA_F16(vf[nf], pb.h, oacc[mi][nf]);
      }
    }
    __builtin_amdgcn_s_setprio(0);
  }

  // epilogue: normalize, write fp16 o [8192][512]
  const int n = nh >> 3, h = nh & 7;
  #pragma unroll
  for (int mi = 0; mi < 2; ++mi) {
    float inv = 1.0f / l_run[mi];
    int row = qt * 128 + w * 32 + 16 * mi + lr;
    _Float16* orow = o_flat + ((size_t)(n * 2048 + row)) * 512 + h * 64;
    #pragma unroll
    for (int nf = 0; nf < 4; ++nf) {
      u32x2 pk2;
      pk2.x = pkrtz(oacc[mi][nf][0] * inv, oacc[mi][nf][1] * inv);
      pk2.y = pkrtz(oacc[mi][nf][2] * inv, oacc[mi][nf][3] * inv);
      *(u32x2*)(orow + 16 * nf + 4 * g) = pk2;
    }
  }
}

// ---------- GEMM3: out = o @ w_proj + b (fp16 -> f32) ----------
__global__ __launch_bounds__(256, 3)
void k_gemm_proj(const _Float16* __restrict__ o_flat,
                 const _Float16* __restrict__ wpT,
                 const float* __restrict__ bias,
                 float* __restrict__ out) {
  __shared__ char As[8192], Bs[8192];
  const int tid = threadIdx.x;
  const int lane = tid & 63, w = tid >> 6;
  const int lr = lane & 15, g = lane >> 4;
  const int m0 = blockIdx.y * 128;
  const int n0 = blockIdx.x * 128;
  const int wr = w >> 1, wc = w & 1;

  f32x4 acc[4][4];
  #pragma unroll
  for (int i = 0; i < 4; ++i)
    #pragma unroll
    for (int j = 0; j < 4; ++j) acc[i][j] = (f32x4){0.f, 0.f, 0.f, 0.f};

  for (int kt = 0; kt < 16; ++kt) {
    const int k0 = kt * 32;
    __syncthreads();
    #pragma unroll
    for (int it = 0; it < 2; ++it) {
      int idx = it * 256 + tid;
      int r = idx >> 2, ch = idx & 3;
      u32x4 d = *(const u32x4*)(o_flat + (m0 + r) * 512 + k0 + ch * 8);
      *(u32x4*)(As + (((r << 6) + (ch << 4)) ^ ((r & 7) << 4))) = d;
    }
    #pragma unroll
    for (int it = 0; it < 2; ++it) {
      int idx = it * 256 + tid;
      int r = idx >> 2, ch = idx & 3;
      u32x4 d = *(const u32x4*)(wpT + (n0 + r) * 512 + k0 + ch * 8);
      *(u32x4*)(Bs + (((r << 6) + (ch << 4)) ^ ((r & 7) << 4))) = d;
    }
    __syncthreads();

    f16x8 af[4], bf[4];
    #pragma unroll
    for (int mi = 0; mi < 4; ++mi) {
      int r = 64 * wr + 16 * mi + lr;
      af[mi] = *(const f16x8*)(As + (((r << 6) + (g << 4)) ^ ((r & 7) << 4)));
    }
    #pragma unroll
    for (int nj = 0; nj < 4; ++nj) {
      int r = 64 * wc + 16 * nj + lr;
      bf[nj] = *(const f16x8*)(Bs + (((r << 6) + (g << 4)) ^ ((r & 7) << 4)));
    }
    __builtin_amdgcn_s_setprio(1);
    #pragma unroll
    for (int mi = 0; mi < 4; ++mi)
      #pragma unroll
      for (int nj = 0; nj < 4; ++nj)
        acc[mi][nj] = MFMA_F16(af[mi], bf[nj], acc[mi][nj]);
    __builtin_amdgcn_s_setprio(0);
  }

  #pragma unroll
  for (int mi = 0; mi < 4; ++mi) {
    int r0f = m0 + 64 * wr + 16 * mi + 4 * g;
    #pragma unroll
    for (int nj = 0; nj < 4; ++nj) {
      int c = n0 + 64 * wc + 16 * nj + lr;
      float b = bias[c];
      #pragma unroll
      for (int i = 0; i < 4; ++i)
        out[(size_t)(r0f + i) * 512 + c] = acc[mi][nj][i] + b;
    }
  }
}

extern "C" void kernel_launch(void* const* d_in, const int* in_sizes, int n_in,
                              void* d_out, int out_size, void* d_ws, size_t ws_size,
                              hipStream_t stream) {
  const float* x      = (const float*)d_in[0];
  const int*   pos_h  = (const int*)d_in[1];
  const int*   pos_w  = (const int*)d_in[2];
  const float* w_qkv  = (const float*)d_in[3];
  const float* w_proj = (const float*)d_in[4];
  const float* b_proj = (const float*)d_in[5];
  float* out = (float*)d_out;

  char* ws = (char*)d_ws;
  size_t off = 0;
  auto alloc = [&](size_t bytes) {
    char* p = ws + off;
    off += (bytes + 1023) & ~(size_t)1023;
    return p;
  };
  _Float16* xh     = (_Float16*)alloc((size_t)8192 * 512 * 2);
  _Float16* qh     = (_Float16*)alloc((size_t)32 * 2048 * 64 * 2);
  _Float16* kh     = (_Float16*)alloc((size_t)32 * 2048 * 64 * 2);
  _Float16* vT     = (_Float16*)alloc((size_t)32 * 2048 * 64 * 2);
  _Float16* o_flat = (_Float16*)alloc((size_t)8192 * 512 * 2);
  _Float16* wqT    = (_Float16*)alloc((size_t)1536 * 512 * 2);
  _Float16* wpT    = (_Float16*)alloc((size_t)512 * 512 * 2);

  hipLaunchKernelGGL(k_prep_x, dim3(4096), dim3(256), 0, stream, x, xh);
  hipLaunchKernelGGL(k_prep_w, dim3(24, 8), dim3(256), 0, stream, w_qkv, wqT, 1536);
  hipLaunchKernelGGL(k_prep_w, dim3(8, 8), dim3(256), 0, stream, w_proj, wpT, 512);
  hipLaunchKernelGGL(k_gemm_qkv, dim3(12, 64), dim3(256), 0, stream,
                     xh, wqT, pos_h, pos_w, qh, kh, vT);
  hipLaunchKernelGGL(k_attn, dim3(512), dim3(256), 0, stream, qh, kh, vT, o_flat);
  hipLaunchKernelGGL(k_gemm_proj, dim3(4, 64), dim3(256), 0, stream, o_flat, wpT, b_proj, out);
}